// Round 5
// baseline (131.662 us; speedup 1.0000x reference)
//
#include <hip/hip_runtime.h>

// NSLayer: per 8x8 matrix x: A = I - x x^T (symmetric),
// out = ((1+w7) I + w0 A + w1 A^2 + ... + w6 A^7) x
//     = M x,  M built by matrix Horner: P=w6A+w5I; P <- P*A + wk*I (x6).
//
// R11 redesign: 1 lane = 1 matrix, packed fp32 (v_pk_fma_f32).
//  - MI355X's 157 TF fp32 requires packed math; scalar v_fma is half rate.
//    All matrices stored as packed row pairs (v2f = even-aligned VGPR pair).
//  - Matmul inner step acc[p][.] += Po[p][r] * A[r][.] is broadcast x vector:
//    VOP3P op_sel broadcasts either half of the Po pair for FREE (no movs):
//    op_sel_hi:[0,1,1] = bcast src0.lo, op_sel:[1,..] op_sel_hi:[1,1,1] =
//    bcast src0.hi. Full 8x8 product = 8 rows x 8 r x 4 pairs = 256 pk-instr.
//  - No lane pairing: zero DPP/shuffles, no duplicated fixed-point work,
//    fully independent lanes. 64 matrices per wave (was 32).
//  - x dies after the Gram; reloaded AFTER the last product (the same wave
//    fetched it ~4500 cyc earlier -> L2-hot, no extra HBM traffic) so the
//    register peak during Horner is A(64)+Po(64)+Pn(64)+temps ~ 220 VGPR
//    -> 2 waves/SIMD, no spill at __launch_bounds__(256,2).
//
// History: R6-R10 pair-scheme (matrix Horner + lane-split triangle + DPP)
// measured 45.5us, VALUBusy 52%, ~219 cyc/matrix -> scalar-issue-bound.
// R9 lesson: never force waves_per_eu=4 (regalloc spilled, 190us).

typedef float v2f __attribute__((ext_vector_type(2)));

// d = a * b (packed, both halves)
__device__ __forceinline__ v2f pk_mul(v2f a, v2f b) {
    v2f d;
    asm("v_pk_mul_f32 %0, %1, %2" : "=v"(d) : "v"(a), "v"(b));
    return d;
}
// acc += a * b (packed, both halves)
__device__ __forceinline__ void pk_fma(v2f &acc, v2f a, v2f b) {
    asm("v_pk_fma_f32 %0, %1, %2, %0" : "+v"(acc) : "v"(a), "v"(b));
}
// d = bcast(a.lo) * b
__device__ __forceinline__ v2f pk_mul_lo(v2f a, v2f b) {
    v2f d;
    asm("v_pk_mul_f32 %0, %1, %2 op_sel:[0,0] op_sel_hi:[0,1]"
        : "=v"(d) : "v"(a), "v"(b));
    return d;
}
// acc += bcast(a.lo) * b
__device__ __forceinline__ void pk_fma_lo(v2f &acc, v2f a, v2f b) {
    asm("v_pk_fma_f32 %0, %1, %2, %0 op_sel:[0,0,0] op_sel_hi:[0,1,1]"
        : "+v"(acc) : "v"(a), "v"(b));
}
// acc += bcast(a.hi) * b
__device__ __forceinline__ void pk_fma_hi(v2f &acc, v2f a, v2f b) {
    asm("v_pk_fma_f32 %0, %1, %2, %0 op_sel:[1,0,0] op_sel_hi:[1,1,1]"
        : "+v"(acc) : "v"(a), "v"(b));
}

#define GE(p, q) G[(p) < (q) ? (p) : (q)][(p) < (q) ? (q) : (p)]

// Pn = Po * A + wk * I, all full 8x8 packed rows. 256 pk + 8 scalar adds.
#define MAT_PROD(Pn, Po, wk)                                              \
    {                                                                     \
        _Pragma("unroll")                                                 \
        for (int p = 0; p < 8; ++p) {                                     \
            v2f a0 = pk_mul_lo(Po[p][0], Ar[0][0]);                       \
            v2f a1 = pk_mul_lo(Po[p][0], Ar[0][1]);                       \
            v2f a2 = pk_mul_lo(Po[p][0], Ar[0][2]);                       \
            v2f a3 = pk_mul_lo(Po[p][0], Ar[0][3]);                       \
            _Pragma("unroll")                                             \
            for (int r = 1; r < 8; ++r) {                                 \
                const v2f br = Po[p][r >> 1];                             \
                if (r & 1) {                                              \
                    pk_fma_hi(a0, br, Ar[r][0]);                          \
                    pk_fma_hi(a1, br, Ar[r][1]);                          \
                    pk_fma_hi(a2, br, Ar[r][2]);                          \
                    pk_fma_hi(a3, br, Ar[r][3]);                          \
                } else {                                                  \
                    pk_fma_lo(a0, br, Ar[r][0]);                          \
                    pk_fma_lo(a1, br, Ar[r][1]);                          \
                    pk_fma_lo(a2, br, Ar[r][2]);                          \
                    pk_fma_lo(a3, br, Ar[r][3]);                          \
                }                                                         \
            }                                                             \
            /* diagonal += wk (compile-time half select) */               \
            if (p == 0) a0.x += (wk); else if (p == 1) a0.y += (wk);      \
            else if (p == 2) a1.x += (wk); else if (p == 3) a1.y += (wk); \
            else if (p == 4) a2.x += (wk); else if (p == 5) a2.y += (wk); \
            else if (p == 6) a3.x += (wk); else a3.y += (wk);             \
            Pn[p][0] = a0; Pn[p][1] = a1; Pn[p][2] = a2; Pn[p][3] = a3;   \
        }                                                                 \
    }

__global__ __launch_bounds__(256, 2)
void ns_poly_kernel(const float* __restrict__ in,
                    const float* __restrict__ wp,
                    float* __restrict__ out)
{
    const int m = blockIdx.x * 256 + threadIdx.x;     // 1 lane = 1 matrix

    const float w0 = wp[0], w1 = wp[1], w2 = wp[2], w3 = wp[3];
    const float w4 = wp[4], w5 = wp[5], w6 = wp[6], w7 = wp[7];

    const float4* __restrict__ xbase =
        reinterpret_cast<const float4*>(in + (size_t)m * 64);

    // ---- load x rows as packed pairs: xr[p][j] = (x[p][2j], x[p][2j+1]) ----
    v2f xr[8][4];
#pragma unroll
    for (int k = 0; k < 16; ++k) {
        const float4 f = xbase[k];
        const int p = k >> 1, jj = (k & 1) * 2;
        xr[p][jj]     = (v2f){f.x, f.y};
        xr[p][jj + 1] = (v2f){f.z, f.w};
    }

    // ---- Gram (upper triangle) via packed dots: G[p][q] = row_p . row_q ----
    float G[8][8];
#pragma unroll
    for (int p = 0; p < 8; ++p)
#pragma unroll
        for (int q = p; q < 8; ++q) {
            v2f a = pk_mul(xr[p][0], xr[q][0]);
            pk_fma(a, xr[p][1], xr[q][1]);
            pk_fma(a, xr[p][2], xr[q][2]);
            pk_fma(a, xr[p][3], xr[q][3]);
            G[p][q] = a.x + a.y;
        }

    // ---- A = I - G, full 8x8 packed rows (x dead after this) ----
    v2f Ar[8][4];
#pragma unroll
    for (int p = 0; p < 8; ++p)
#pragma unroll
        for (int j = 0; j < 4; ++j)
            Ar[p][j] = (v2f){
                ((p == 2 * j)     ? 1.0f : 0.0f) - GE(p, 2 * j),
                ((p == 2 * j + 1) ? 1.0f : 0.0f) - GE(p, 2 * j + 1)};

    // ---- matrix Horner: P = w6 A + w5 I, then 6 products ----
    v2f P[8][4], Q[8][4];
    const v2f w6v = (v2f){w6, w6};
#pragma unroll
    for (int p = 0; p < 8; ++p)
#pragma unroll
        for (int j = 0; j < 4; ++j)
            P[p][j] = pk_mul(w6v, Ar[p][j]);
    P[0][0].x += w5; P[1][0].y += w5; P[2][1].x += w5; P[3][1].y += w5;
    P[4][2].x += w5; P[5][2].y += w5; P[6][3].x += w5; P[7][3].y += w5;

    MAT_PROD(Q, P, w4);           // w6 A^2 + w5 A + w4 I
    MAT_PROD(P, Q, w3);
    MAT_PROD(Q, P, w2);
    MAT_PROD(P, Q, w1);
    MAT_PROD(Q, P, w0);           // R = w6 A^6 + ... + w0 I
    MAT_PROD(P, Q, 1.0f + w7);    // M = R A + (1+w7) I   (final in P)

    // ---- reload x (L2-hot: this wave fetched it earlier) ----
#pragma unroll
    for (int k = 0; k < 16; ++k) {
        const float4 f = xbase[k];
        const int p = k >> 1, jj = (k & 1) * 2;
        xr[p][jj]     = (v2f){f.x, f.y};
        xr[p][jj + 1] = (v2f){f.z, f.w};
    }

    // ---- out = x + M x, row-wise: out[p] = x[p] + sum_q M[p][q] * x[q] ----
    float4* __restrict__ obase = reinterpret_cast<float4*>(out + (size_t)m * 64);
#pragma unroll
    for (int p = 0; p < 8; ++p) {
        v2f o0 = xr[p][0], o1 = xr[p][1], o2 = xr[p][2], o3 = xr[p][3];
#pragma unroll
        for (int q = 0; q < 8; ++q) {
            const v2f mq = P[p][q >> 1];
            if (q & 1) {
                pk_fma_hi(o0, mq, xr[q][0]);
                pk_fma_hi(o1, mq, xr[q][1]);
                pk_fma_hi(o2, mq, xr[q][2]);
                pk_fma_hi(o3, mq, xr[q][3]);
            } else {
                pk_fma_lo(o0, mq, xr[q][0]);
                pk_fma_lo(o1, mq, xr[q][1]);
                pk_fma_lo(o2, mq, xr[q][2]);
                pk_fma_lo(o3, mq, xr[q][3]);
            }
        }
        obase[p * 2]     = make_float4(o0.x, o0.y, o1.x, o1.y);
        obase[p * 2 + 1] = make_float4(o2.x, o2.y, o3.x, o3.y);
    }
}

extern "C" void kernel_launch(void* const* d_in, const int* in_sizes, int n_in,
                              void* d_out, int out_size, void* d_ws, size_t ws_size,
                              hipStream_t stream)
{
    const float* in = (const float*)d_in[0];
    const float* w  = (const float*)d_in[1];
    float* outp     = (float*)d_out;

    const int nmat   = in_sizes[0] / 64;   // 262144 matrices
    const int blocks = nmat / 256;         // 1 matrix per thread
    ns_poly_kernel<<<blocks, 256, 0, stream>>>(in, w, outp);
}

// Round 6
// 126.869 us; speedup vs baseline: 1.0378x; 1.0378x over previous
//
#include <hip/hip_runtime.h>

// NSLayer: per 8x8 matrix x: A = I - x x^T (symmetric),
// out = (1+w7) x + sum_{k=1..7} w_{k-1} A^k x.
//
// R12 = R10's pair scheme + R11's packed math, restructured to avoid R11's
// register-demotion failure:
//  - 2 lanes per matrix, lane h owns COLUMNS 4h..4h+3; rows half-permuted
//    (p<4 -> 4h+p, p>=4 -> 4(1-h)+(p-4)); partner exchange = DPP quad_perm
//    lane^1 swap (proven R10). Gram: S + pswap(S) as before.
//  - POWER form, not Horner: acc = (1+w7) x; y = x; 7x { y <- A y;
//    acc += w_{k-1} y }. x dies at init -> peak live = Ar(64 full packed
//    rows) + y(32) + acc(32) + 16 transient ~ 150 VGPR. R11 needed ~210
//    and the backend demoted arrays to scratch (WRITE 147MB, 56us).
//  - matvec packed over the lane's 2 column-pairs via v_pk_fma_f32 with
//    op_sel broadcast of either half of the Ar row-pair (encodings proven
//    correct in R11: it PASSED, just slow from scratch). Per step:
//    2j x 8p x (1 pk_mul + 7 pk_fma) + 16 acc pk_fma = 144 instr vs R10's
//    176 scalar; ~1350 instr/lane total vs R10's ~1650, at 2 FLOP/instr.
// Health check for this shape: VGPR should be ~150-170 and WRITE_SIZE
// ~65.5MB. VGPR <=120 with WRITE >> 65.5MB means demotion again.
//
// History: R10 (scalar matrix Horner, DPP triangle split) = 45.5us,
// VALUBusy 52%. R9 lesson: never force waves_per_eu >= 3.

typedef float v2f __attribute__((ext_vector_type(2)));

// ---- packed fp32 primitives (encodings verified by R11's passing run) ----
__device__ __forceinline__ v2f pk_mul(v2f a, v2f b) {
    v2f d;
    asm("v_pk_mul_f32 %0, %1, %2" : "=v"(d) : "v"(a), "v"(b));
    return d;
}
__device__ __forceinline__ void pk_fma(v2f &acc, v2f a, v2f b) {
    asm("v_pk_fma_f32 %0, %1, %2, %0" : "+v"(acc) : "v"(a), "v"(b));
}
// d = bcast(a.lo) * b
__device__ __forceinline__ v2f pk_mul_lo(v2f a, v2f b) {
    v2f d;
    asm("v_pk_mul_f32 %0, %1, %2 op_sel:[0,0] op_sel_hi:[0,1]"
        : "=v"(d) : "v"(a), "v"(b));
    return d;
}
// acc += bcast(a.lo) * b
__device__ __forceinline__ void pk_fma_lo(v2f &acc, v2f a, v2f b) {
    asm("v_pk_fma_f32 %0, %1, %2, %0 op_sel:[0,0,0] op_sel_hi:[0,1,1]"
        : "+v"(acc) : "v"(a), "v"(b));
}
// acc += bcast(a.hi) * b
__device__ __forceinline__ void pk_fma_hi(v2f &acc, v2f a, v2f b) {
    asm("v_pk_fma_f32 %0, %1, %2, %0 op_sel:[1,0,0] op_sel_hi:[1,1,1]"
        : "+v"(acc) : "v"(a), "v"(b));
}

// lane^1 partner swap as DPP quad_perm [1,0,3,2] (ctrl 0xB1), proven R10.
__device__ __forceinline__ float pswap(float x)
{
    return __builtin_bit_cast(float,
        __builtin_amdgcn_update_dpp(0, __builtin_bit_cast(int, x),
                                    0xB1, 0xF, 0xF, true));
}

#define SE(p, q) S[(p) < (q) ? (p) : (q)][(p) < (q) ? (q) : (p)]
#define AE(p, q) A[(p) < (q) ? (p) : (q)][(p) < (q) ? (q) : (p)]

// One power step: n = A*y (slab matvec, packed), y <- n, acc += wk * n.
#define POW_STEP(wk)                                                      \
    {                                                                     \
        const v2f wv = (v2f){(wk), (wk)};                                 \
        _Pragma("unroll")                                                 \
        for (int j = 0; j < 2; ++j) {                                     \
            v2f n[8];                                                     \
            _Pragma("unroll")                                             \
            for (int p = 0; p < 8; ++p) {                                 \
                v2f a = pk_mul_lo(Ar[p][0], y[j][0]);                     \
                pk_fma_hi(a, Ar[p][0], y[j][1]);                          \
                pk_fma_lo(a, Ar[p][1], y[j][2]);                          \
                pk_fma_hi(a, Ar[p][1], y[j][3]);                          \
                pk_fma_lo(a, Ar[p][2], y[j][4]);                          \
                pk_fma_hi(a, Ar[p][2], y[j][5]);                          \
                pk_fma_lo(a, Ar[p][3], y[j][6]);                          \
                pk_fma_hi(a, Ar[p][3], y[j][7]);                          \
                n[p] = a;                                                 \
            }                                                             \
            _Pragma("unroll")                                             \
            for (int p = 0; p < 8; ++p) {                                 \
                y[j][p] = n[p];                                           \
                pk_fma(acc[j][p], wv, n[p]);                              \
            }                                                             \
        }                                                                 \
    }

__global__ __launch_bounds__(256, 2)
void ns_poly_kernel(const float* __restrict__ in,
                    const float* __restrict__ wp,
                    float* __restrict__ out)
{
    const int tid = threadIdx.x;
    const int m   = blockIdx.x * 128 + (tid >> 1);   // matrix index
    const int h   = tid & 1;                          // column-half owner

    const float w0 = wp[0], w1 = wp[1], w2 = wp[2], w3 = wp[3];
    const float w4 = wp[4], w5 = wp[5], w6 = wp[6], w7 = wp[7];

    // ---- column-slab loads (transpose by addressing), packed col-pairs ----
    // y[j][p] = (col 4h+2j, col 4h+2j+1) at permuted row p.
    const float* bp      = in + (size_t)m * 64 + h * 4;
    const float* baseOwn = bp + h * 32;
    const float* basePar = bp + (1 - h) * 32;

    v2f y[2][8];
#pragma unroll
    for (int p = 0; p < 4; ++p) {
        const float4 v = *reinterpret_cast<const float4*>(baseOwn + p * 8);
        y[0][p] = (v2f){v.x, v.y};
        y[1][p] = (v2f){v.z, v.w};
    }
#pragma unroll
    for (int p = 0; p < 4; ++p) {
        const float4 v = *reinterpret_cast<const float4*>(basePar + p * 8);
        y[0][4 + p] = (v2f){v.x, v.y};
        y[1][4 + p] = (v2f){v.z, v.w};
    }

    // ---- partial Gram S[p][q] over my 4 columns (upper triangle) ----
    float S[8][8];
#pragma unroll
    for (int p = 0; p < 8; ++p)
#pragma unroll
        for (int q = p; q < 8; ++q) {
            v2f a = pk_mul(y[0][p], y[0][q]);
            pk_fma(a, y[1][p], y[1][q]);
            S[p][q] = a.x + a.y;
        }

    // ---- A = I - S - partner(S) (upper triangle scalars) ----
    float A[8][8];
#pragma unroll
    for (int p = 0; p < 8; ++p)
#pragma unroll
        for (int q = p; q < 8; ++q) {
            const float other = pswap(SE((p) ^ 4, (q) ^ 4));
            A[p][q] = (p == q ? 1.0f : 0.0f) - S[p][q] - other;
        }

    // ---- pack A into full rows of q-pairs for op_sel broadcast ----
    v2f Ar[8][4];
#pragma unroll
    for (int p = 0; p < 8; ++p)
#pragma unroll
        for (int jq = 0; jq < 4; ++jq)
            Ar[p][jq] = (v2f){AE(p, 2 * jq), AE(p, 2 * jq + 1)};

    // ---- power iteration: acc = (1+w7) x; 7x { y <- A y; acc += wk y } ----
    v2f acc[2][8];
    const v2f w7v = (v2f){1.0f + w7, 1.0f + w7};
#pragma unroll
    for (int j = 0; j < 2; ++j)
#pragma unroll
        for (int p = 0; p < 8; ++p)
            acc[j][p] = pk_mul(w7v, y[j][p]);

    POW_STEP(w0);
    POW_STEP(w1);
    POW_STEP(w2);
    POW_STEP(w3);
    POW_STEP(w4);
    POW_STEP(w5);
    POW_STEP(w6);

    // ---- column-slab stores (transpose by addressing) ----
    float* obp     = out + (size_t)m * 64 + h * 4;
    float* oandOwn = obp + h * 32;
    float* oandPar = obp + (1 - h) * 32;
#pragma unroll
    for (int p = 0; p < 4; ++p)
        *reinterpret_cast<float4*>(oandOwn + p * 8) =
            make_float4(acc[0][p].x, acc[0][p].y, acc[1][p].x, acc[1][p].y);
#pragma unroll
    for (int p = 0; p < 4; ++p)
        *reinterpret_cast<float4*>(oandPar + p * 8) =
            make_float4(acc[0][4 + p].x, acc[0][4 + p].y,
                        acc[1][4 + p].x, acc[1][4 + p].y);
}

extern "C" void kernel_launch(void* const* d_in, const int* in_sizes, int n_in,
                              void* d_out, int out_size, void* d_ws, size_t ws_size,
                              hipStream_t stream)
{
    const float* in = (const float*)d_in[0];
    const float* w  = (const float*)d_in[1];
    float* outp     = (float*)d_out;

    const int nmat   = in_sizes[0] / 64;   // 262144 matrices
    const int blocks = nmat / 128;         // 128 matrices per 256-thread block
    ns_poly_kernel<<<blocks, 256, 0, stream>>>(in, w, outp);
}

// Round 7
// 126.605 us; speedup vs baseline: 1.0399x; 1.0021x over previous
//
#include <hip/hip_runtime.h>

// NSLayer: per 8x8 matrix x: A = I - x x^T (symmetric),
// out = (1+w7) x + sum_{k=1..7} w_{k-1} A^k x.
//
// Structure (R12, unchanged body):
//  - 2 lanes per matrix, lane h owns COLUMNS 4h..4h+3; rows half-permuted
//    (p<4 -> 4h+p, p>=4 -> 4(1-h)+(p-4)); partner exchange = DPP quad_perm
//    lane^1 swap. Gram: S + pswap(S).
//  - POWER form: acc = (1+w7) x; y = x; 7x { y <- A y; acc += w_{k-1} y }.
//    Peak live ~ Ar(64) + y(32) + acc(32) + transient -> 76 VGPR measured.
//  - matvec packed via v_pk_fma_f32 with op_sel broadcast of either half of
//    the Ar row-pair (encodings proven R11/R12: both passed).
//
// R13 change: lift the occupancy cap. Measured evidence that launch_bounds'
// 2nd arg acts as a runtime waves/SIMD MAX: R9 (256,4)+VGPR64 -> 39% occ
// (~cap 4, though regs allow 8); all (256,2) rounds -> 15-20% occ (~cap 2)
// at VGPR 76-116 (regs allow 4-6). Three different kernels (1650/1650/1400
// instr) all floor at 46-49us with VALUBusy 52/52/32% -> latency-bound at
// ~2 resident waves/SIMD, issue floor ~9.5us. Fix: __launch_bounds__(256)
// (flat wg size only) + amdgpu_waves_per_eu(2, 8): min 2 keeps regalloc
// pressure identical (expect same 76 VGPR, no spill), max 8 lets the HW
// schedule 4-6 waves/SIMD (VGPR-bound).
// Health check: VGPR must stay ~76 and WRITE_SIZE ~65.5MB; VGPR drop +
// WRITE balloon = allocator chased occupancy and spilled (R9 mode) ->
// fall back to amdgpu_waves_per_eu(2, 4).

typedef float v2f __attribute__((ext_vector_type(2)));

// ---- packed fp32 primitives (encodings verified by R11/R12 passing runs) ----
__device__ __forceinline__ v2f pk_mul(v2f a, v2f b) {
    v2f d;
    asm("v_pk_mul_f32 %0, %1, %2" : "=v"(d) : "v"(a), "v"(b));
    return d;
}
__device__ __forceinline__ void pk_fma(v2f &acc, v2f a, v2f b) {
    asm("v_pk_fma_f32 %0, %1, %2, %0" : "+v"(acc) : "v"(a), "v"(b));
}
// d = bcast(a.lo) * b
__device__ __forceinline__ v2f pk_mul_lo(v2f a, v2f b) {
    v2f d;
    asm("v_pk_mul_f32 %0, %1, %2 op_sel:[0,0] op_sel_hi:[0,1]"
        : "=v"(d) : "v"(a), "v"(b));
    return d;
}
// acc += bcast(a.lo) * b
__device__ __forceinline__ void pk_fma_lo(v2f &acc, v2f a, v2f b) {
    asm("v_pk_fma_f32 %0, %1, %2, %0 op_sel:[0,0,0] op_sel_hi:[0,1,1]"
        : "+v"(acc) : "v"(a), "v"(b));
}
// acc += bcast(a.hi) * b
__device__ __forceinline__ void pk_fma_hi(v2f &acc, v2f a, v2f b) {
    asm("v_pk_fma_f32 %0, %1, %2, %0 op_sel:[1,0,0] op_sel_hi:[1,1,1]"
        : "+v"(acc) : "v"(a), "v"(b));
}

// lane^1 partner swap as DPP quad_perm [1,0,3,2] (ctrl 0xB1), proven R10.
__device__ __forceinline__ float pswap(float x)
{
    return __builtin_bit_cast(float,
        __builtin_amdgcn_update_dpp(0, __builtin_bit_cast(int, x),
                                    0xB1, 0xF, 0xF, true));
}

#define SE(p, q) S[(p) < (q) ? (p) : (q)][(p) < (q) ? (q) : (p)]
#define AE(p, q) A[(p) < (q) ? (p) : (q)][(p) < (q) ? (q) : (p)]

// One power step: n = A*y (slab matvec, packed), y <- n, acc += wk * n.
#define POW_STEP(wk)                                                      \
    {                                                                     \
        const v2f wv = (v2f){(wk), (wk)};                                 \
        _Pragma("unroll")                                                 \
        for (int j = 0; j < 2; ++j) {                                     \
            v2f n[8];                                                     \
            _Pragma("unroll")                                             \
            for (int p = 0; p < 8; ++p) {                                 \
                v2f a = pk_mul_lo(Ar[p][0], y[j][0]);                     \
                pk_fma_hi(a, Ar[p][0], y[j][1]);                          \
                pk_fma_lo(a, Ar[p][1], y[j][2]);                          \
                pk_fma_hi(a, Ar[p][1], y[j][3]);                          \
                pk_fma_lo(a, Ar[p][2], y[j][4]);                          \
                pk_fma_hi(a, Ar[p][2], y[j][5]);                          \
                pk_fma_lo(a, Ar[p][3], y[j][6]);                          \
                pk_fma_hi(a, Ar[p][3], y[j][7]);                          \
                n[p] = a;                                                 \
            }                                                             \
            _Pragma("unroll")                                             \
            for (int p = 0; p < 8; ++p) {                                 \
                y[j][p] = n[p];                                           \
                pk_fma(acc[j][p], wv, n[p]);                              \
            }                                                             \
        }                                                                 \
    }

__global__ __launch_bounds__(256)
__attribute__((amdgpu_waves_per_eu(2, 8)))
void ns_poly_kernel(const float* __restrict__ in,
                    const float* __restrict__ wp,
                    float* __restrict__ out)
{
    const int tid = threadIdx.x;
    const int m   = blockIdx.x * 128 + (tid >> 1);   // matrix index
    const int h   = tid & 1;                          // column-half owner

    const float w0 = wp[0], w1 = wp[1], w2 = wp[2], w3 = wp[3];
    const float w4 = wp[4], w5 = wp[5], w6 = wp[6], w7 = wp[7];

    // ---- column-slab loads (transpose by addressing), packed col-pairs ----
    // y[j][p] = (col 4h+2j, col 4h+2j+1) at permuted row p.
    const float* bp      = in + (size_t)m * 64 + h * 4;
    const float* baseOwn = bp + h * 32;
    const float* basePar = bp + (1 - h) * 32;

    v2f y[2][8];
#pragma unroll
    for (int p = 0; p < 4; ++p) {
        const float4 v = *reinterpret_cast<const float4*>(baseOwn + p * 8);
        y[0][p] = (v2f){v.x, v.y};
        y[1][p] = (v2f){v.z, v.w};
    }
#pragma unroll
    for (int p = 0; p < 4; ++p) {
        const float4 v = *reinterpret_cast<const float4*>(basePar + p * 8);
        y[0][4 + p] = (v2f){v.x, v.y};
        y[1][4 + p] = (v2f){v.z, v.w};
    }

    // ---- partial Gram S[p][q] over my 4 columns (upper triangle) ----
    float S[8][8];
#pragma unroll
    for (int p = 0; p < 8; ++p)
#pragma unroll
        for (int q = p; q < 8; ++q) {
            v2f a = pk_mul(y[0][p], y[0][q]);
            pk_fma(a, y[1][p], y[1][q]);
            S[p][q] = a.x + a.y;
        }

    // ---- A = I - S - partner(S) (upper triangle scalars) ----
    float A[8][8];
#pragma unroll
    for (int p = 0; p < 8; ++p)
#pragma unroll
        for (int q = p; q < 8; ++q) {
            const float other = pswap(SE((p) ^ 4, (q) ^ 4));
            A[p][q] = (p == q ? 1.0f : 0.0f) - S[p][q] - other;
        }

    // ---- pack A into full rows of q-pairs for op_sel broadcast ----
    v2f Ar[8][4];
#pragma unroll
    for (int p = 0; p < 8; ++p)
#pragma unroll
        for (int jq = 0; jq < 4; ++jq)
            Ar[p][jq] = (v2f){AE(p, 2 * jq), AE(p, 2 * jq + 1)};

    // ---- power iteration: acc = (1+w7) x; 7x { y <- A y; acc += wk y } ----
    v2f acc[2][8];
    const v2f w7v = (v2f){1.0f + w7, 1.0f + w7};
#pragma unroll
    for (int j = 0; j < 2; ++j)
#pragma unroll
        for (int p = 0; p < 8; ++p)
            acc[j][p] = pk_mul(w7v, y[j][p]);

    POW_STEP(w0);
    POW_STEP(w1);
    POW_STEP(w2);
    POW_STEP(w3);
    POW_STEP(w4);
    POW_STEP(w5);
    POW_STEP(w6);

    // ---- column-slab stores (transpose by addressing) ----
    float* obp     = out + (size_t)m * 64 + h * 4;
    float* oandOwn = obp + h * 32;
    float* oandPar = obp + (1 - h) * 32;
#pragma unroll
    for (int p = 0; p < 4; ++p)
        *reinterpret_cast<float4*>(oandOwn + p * 8) =
            make_float4(acc[0][p].x, acc[0][p].y, acc[1][p].x, acc[1][p].y);
#pragma unroll
    for (int p = 0; p < 4; ++p)
        *reinterpret_cast<float4*>(oandPar + p * 8) =
            make_float4(acc[0][4 + p].x, acc[0][4 + p].y,
                        acc[1][4 + p].x, acc[1][4 + p].y);
}

extern "C" void kernel_launch(void* const* d_in, const int* in_sizes, int n_in,
                              void* d_out, int out_size, void* d_ws, size_t ws_size,
                              hipStream_t stream)
{
    const float* in = (const float*)d_in[0];
    const float* w  = (const float*)d_in[1];
    float* outp     = (float*)d_out;

    const int nmat   = in_sizes[0] / 64;   // 262144 matrices
    const int blocks = nmat / 128;         // 128 matrices per 256-thread block
    ns_poly_kernel<<<blocks, 256, 0, stream>>>(in, w, outp);
}

// Round 9
// 119.597 us; speedup vs baseline: 1.1009x; 1.0586x over previous
//
#include <hip/hip_runtime.h>

// NSLayer: per 8x8 matrix x: A = I - x x^T (symmetric),
// out = (1+w7) x + sum_{k=1..7} w_{k-1} A^k x.
//
// R14 (resubmitted R15: prior run died to infra "container failed twice",
// same as R6; source re-audited — LDS bounds, swizzle involution, bank
// floor, race freedom — unchanged):
// coalesced I/O via LDS transpose staging + R12's packed compute.
// Diagnosis: R8/R10/R12/R13 (1650/1650/1400/1400 instr) all ~46-52us at
// ~100MB => ~2 TB/s. Compute halved, time constant -> memory wall. Old
// loads/stores were 16B granules scattered 64-ways per instruction (256B
// matrix stride): ~1024 sector-requests/wave => ~1/4 of line bandwidth
// => 2 TB/s. Fix: every global instruction is lane i <-> bytes [16i,16i+16)
// of a contiguous 1KB block (the 6.3 TB/s streaming pattern); the
// matrix<->lane transpose happens in LDS.
//
// LDS plan (per wave, wave-private 8KB = 32 matrices, NO barriers):
//   stage-in : 8x { gsrc[C] -> L[s(C)] }        C = it*64+lane, contiguous
//   frag-read: 8x { L[s(l*16 + g*2 + h)] }      lane pair l, col-half h
//   frag-write: 8x { acc -> L[s(l*16+g*2+h)] }
//   drain    : 8x { L[s(C)] -> gdst[C] }        contiguous
// with chunk swizzle s(C) = C ^ (((C>>4)&3)<<1)  (involutive; bits 4-5 of C
// = matrix index bits, XORed into bits 1-2). Bank check per instruction:
// f4%8 spans all 8 4-bank groups, 8 lanes each = the 1KB floor ->
// conflict-free for all four phases.
// Natural row layout now (no half-permute): partner Gram merge is
// pswap at the SAME (p,q).  lgkmcnt(0) fences guard cross-lane LDS handoff
// (same-wave lockstep, no __syncthreads needed).
//
// Compute (proven R12): POWER form acc = (1+w7)x; 7x { y <- A y;
// acc += wk y }, packed v_pk_fma_f32 with op_sel broadcast.
// History lessons: R9 never force waves_per_eu (spill); R11 1-lane/matrix
// demotes to scratch; R13 waves_per_eu(2,8) no effect on residency.

typedef float v2f __attribute__((ext_vector_type(2)));

// ---- packed fp32 primitives (encodings proven R11/R12) ----
__device__ __forceinline__ v2f pk_mul(v2f a, v2f b) {
    v2f d;
    asm("v_pk_mul_f32 %0, %1, %2" : "=v"(d) : "v"(a), "v"(b));
    return d;
}
__device__ __forceinline__ void pk_fma(v2f &acc, v2f a, v2f b) {
    asm("v_pk_fma_f32 %0, %1, %2, %0" : "+v"(acc) : "v"(a), "v"(b));
}
__device__ __forceinline__ v2f pk_mul_lo(v2f a, v2f b) {
    v2f d;
    asm("v_pk_mul_f32 %0, %1, %2 op_sel:[0,0] op_sel_hi:[0,1]"
        : "=v"(d) : "v"(a), "v"(b));
    return d;
}
__device__ __forceinline__ void pk_fma_lo(v2f &acc, v2f a, v2f b) {
    asm("v_pk_fma_f32 %0, %1, %2, %0 op_sel:[0,0,0] op_sel_hi:[0,1,1]"
        : "+v"(acc) : "v"(a), "v"(b));
}
__device__ __forceinline__ void pk_fma_hi(v2f &acc, v2f a, v2f b) {
    asm("v_pk_fma_f32 %0, %1, %2, %0 op_sel:[1,0,0] op_sel_hi:[1,1,1]"
        : "+v"(acc) : "v"(a), "v"(b));
}

// lane^1 partner swap as DPP quad_perm [1,0,3,2] (ctrl 0xB1), proven R10.
__device__ __forceinline__ float pswap(float x)
{
    return __builtin_bit_cast(float,
        __builtin_amdgcn_update_dpp(0, __builtin_bit_cast(int, x),
                                    0xB1, 0xF, 0xF, true));
}

#define AE(p, q) A[(p) < (q) ? (p) : (q)][(p) < (q) ? (q) : (p)]

// One power step: n = A*y (slab matvec, packed), y <- n, acc += wk * n.
#define POW_STEP(wk)                                                      \
    {                                                                     \
        const v2f wv = (v2f){(wk), (wk)};                                 \
        _Pragma("unroll")                                                 \
        for (int j = 0; j < 2; ++j) {                                     \
            v2f n[8];                                                     \
            _Pragma("unroll")                                             \
            for (int p = 0; p < 8; ++p) {                                 \
                v2f a = pk_mul_lo(Ar[p][0], y[j][0]);                     \
                pk_fma_hi(a, Ar[p][0], y[j][1]);                          \
                pk_fma_lo(a, Ar[p][1], y[j][2]);                          \
                pk_fma_hi(a, Ar[p][1], y[j][3]);                          \
                pk_fma_lo(a, Ar[p][2], y[j][4]);                          \
                pk_fma_hi(a, Ar[p][2], y[j][5]);                          \
                pk_fma_lo(a, Ar[p][3], y[j][6]);                          \
                pk_fma_hi(a, Ar[p][3], y[j][7]);                          \
                n[p] = a;                                                 \
            }                                                             \
            _Pragma("unroll")                                             \
            for (int p = 0; p < 8; ++p) {                                 \
                y[j][p] = n[p];                                           \
                pk_fma(acc[j][p], wv, n[p]);                              \
            }                                                             \
        }                                                                 \
    }

__global__ __launch_bounds__(256)
void ns_poly_kernel(const float* __restrict__ in,
                    const float* __restrict__ wp,
                    float* __restrict__ out)
{
    __shared__ float4 lds[2048];                      // 32 KB: 4 waves x 8 KB

    const int tid  = threadIdx.x;
    const int wave = tid >> 6;
    const int lane = tid & 63;
    const int l    = lane >> 1;                       // matrix-in-wave 0..31
    const int h    = lane & 1;                        // column-half owner

    const float w0 = wp[0], w1 = wp[1], w2 = wp[2], w3 = wp[3];
    const float w4 = wp[4], w5 = wp[5], w6 = wp[6], w7 = wp[7];

    // wave's 32 matrices, 16 float4 each
    const int wave_mat0 = blockIdx.x * 128 + wave * 32;
    const float4* __restrict__ gsrc =
        reinterpret_cast<const float4*>(in) + (size_t)wave_mat0 * 16;
    float4* __restrict__ gdst =
        reinterpret_cast<float4*>(out) + (size_t)wave_mat0 * 16;
    float4* L = lds + wave * 512;                     // wave-private 8 KB

    // ---- stage in: contiguous global reads -> swizzled LDS ----
#pragma unroll
    for (int it = 0; it < 8; ++it) {
        const int C  = it * 64 + lane;
        const int Cs = C ^ (((C >> 4) & 3) << 1);
        L[Cs] = gsrc[C];
    }
    asm volatile("s_waitcnt lgkmcnt(0)" ::: "memory");

    // ---- fragment read: rows g=0..7, my col-half; natural layout ----
    // chunk-in-wave = l*16 + g*2 + h, swizzled with (l&3)<<1
    v2f y[2][8];
#pragma unroll
    for (int g = 0; g < 8; ++g) {
        const int f4 = (l * 16 + g * 2 + h) ^ ((l & 3) << 1);
        const float4 v = L[f4];
        y[0][g] = (v2f){v.x, v.y};
        y[1][g] = (v2f){v.z, v.w};
    }

    // ---- partial Gram over my 4 columns (upper triangle) ----
    float S[8][8];
#pragma unroll
    for (int p = 0; p < 8; ++p)
#pragma unroll
        for (int q = p; q < 8; ++q) {
            v2f a = pk_mul(y[0][p], y[0][q]);
            pk_fma(a, y[1][p], y[1][q]);
            S[p][q] = a.x + a.y;
        }

    // ---- A = I - S - partner(S): natural frame, pswap at same (p,q) ----
    float A[8][8];
#pragma unroll
    for (int p = 0; p < 8; ++p)
#pragma unroll
        for (int q = p; q < 8; ++q) {
            const float other = pswap(S[p][q]);
            A[p][q] = (p == q ? 1.0f : 0.0f) - S[p][q] - other;
        }

    // ---- pack A rows into q-pairs for op_sel broadcast ----
    v2f Ar[8][4];
#pragma unroll
    for (int p = 0; p < 8; ++p)
#pragma unroll
        for (int jq = 0; jq < 4; ++jq)
            Ar[p][jq] = (v2f){AE(p, 2 * jq), AE(p, 2 * jq + 1)};

    // ---- power iteration: acc = (1+w7) x; 7x { y <- A y; acc += wk y } ----
    v2f acc[2][8];
    const v2f w7v = (v2f){1.0f + w7, 1.0f + w7};
#pragma unroll
    for (int j = 0; j < 2; ++j)
#pragma unroll
        for (int p = 0; p < 8; ++p)
            acc[j][p] = pk_mul(w7v, y[j][p]);

    POW_STEP(w0);
    POW_STEP(w1);
    POW_STEP(w2);
    POW_STEP(w3);
    POW_STEP(w4);
    POW_STEP(w5);
    POW_STEP(w6);

    // ---- fragment write back to LDS (swizzled, conflict-free) ----
#pragma unroll
    for (int g = 0; g < 8; ++g) {
        const int f4 = (l * 16 + g * 2 + h) ^ ((l & 3) << 1);
        L[f4] = make_float4(acc[0][g].x, acc[0][g].y,
                            acc[1][g].x, acc[1][g].y);
    }
    asm volatile("s_waitcnt lgkmcnt(0)" ::: "memory");

    // ---- drain: swizzled LDS -> contiguous global stores ----
#pragma unroll
    for (int it = 0; it < 8; ++it) {
        const int C  = it * 64 + lane;
        const int Cs = C ^ (((C >> 4) & 3) << 1);
        gdst[C] = L[Cs];
    }
}

extern "C" void kernel_launch(void* const* d_in, const int* in_sizes, int n_in,
                              void* d_out, int out_size, void* d_ws, size_t ws_size,
                              hipStream_t stream)
{
    const float* in = (const float*)d_in[0];
    const float* w  = (const float*)d_in[1];
    float* outp     = (float*)d_out;

    const int nmat   = in_sizes[0] / 64;   // 262144 matrices
    const int blocks = nmat / 128;         // 128 matrices per 256-thread block
    ns_poly_kernel<<<blocks, 256, 0, stream>>>(in, w, outp);
}